// Round 9
// baseline (284.684 us; speedup 1.0000x reference)
//
#include <hip/hip_runtime.h>
#include <stdint.h>

#define BB 8            // bucket = dst >> 8 (256 dsts per bucket)
#define BSZ 256
#define NBMAX 512       // max buckets per relation (100000>>8 = 391)
#define CAP 6144        // bucket edge capacity (mean ~4096, ~32 sigma margin)

typedef _Float16 half8 __attribute__((ext_vector_type(8)));

// ---------------------------------------------------------------------------
// binproj: FUSED kbin + proj_tile (independent work, one launch so the
// memory-bound binning blocks overlap the VALU/LDS-bound projection blocks).
// Blocks [0, nbin): kbin (identical algorithm to known-good K1).
// Blocks [nbin, ...): projection, 2x 64-node tiles per 512-thread block,
// weight LDS shared between the two tiles (50KB -> 3 blocks/CU).
union BpSm {
    struct { int cnt[NBMAX]; int base[NBMAX]; } bin;
    struct { float xs[2][64][68]; float wyl[64][32]; float wsl[64][32]; } pj;
};

__global__ void __launch_bounds__(512) binproj(
    const int* __restrict__ e1, const int* __restrict__ e2, int E,
    int* __restrict__ gcur1, int* __restrict__ gcur2,
    unsigned int* __restrict__ P1, unsigned int* __restrict__ P2,
    int blocksPerRel, int nbin,
    const float* __restrict__ x1, const float* __restrict__ Wy1, const float* __restrict__ Ws1,
    _Float16* __restrict__ y1, _Float16* __restrict__ s1, int N1, int tb1,
    const float* __restrict__ x2, const float* __restrict__ Wy2, const float* __restrict__ Ws2,
    _Float16* __restrict__ y2, _Float16* __restrict__ s2, int N2) {
    __shared__ BpSm sm;
    int tid = threadIdx.x;

    if (blockIdx.x < (unsigned)nbin) {
        // ---------------- kbin path (frozen algorithm) ----------------
        int rel = blockIdx.x >= blocksPerRel;
        int blk = rel ? blockIdx.x - blocksPerRel : blockIdx.x;
        const int* edge = rel ? e2 : e1;
        int* gcur = rel ? gcur2 : gcur1;
        unsigned int* P = rel ? P2 : P1;
        for (int i = tid; i < NBMAX; i += 512) sm.bin.cnt[i] = 0;
        __syncthreads();
        int cbase = blk * 8192;
        int src[16], dst[16], rk[16];
#pragma unroll
        for (int k = 0; k < 16; k++) {
            int i = cbase + k * 512 + tid;
            if (i < E) {
                src[k] = edge[i];
                dst[k] = edge[E + i];
                rk[k] = atomicAdd(&sm.bin.cnt[dst[k] >> BB], 1);
            }
        }
        __syncthreads();
        for (int b = tid; b < NBMAX; b += 512)
            sm.bin.base[b] = sm.bin.cnt[b] ? atomicAdd(&gcur[b], sm.bin.cnt[b]) : 0;
        __syncthreads();
#pragma unroll
        for (int k = 0; k < 16; k++) {
            int i = cbase + k * 512 + tid;
            if (i < E) {
                int b = dst[k] >> BB;
                int slot = sm.bin.base[b] + rk[k];
                if (slot < CAP)
                    P[(size_t)b * CAP + slot] =
                        ((unsigned)src[k] << BB) | (unsigned)(dst[k] & (BSZ - 1));
            }
        }
    } else {
        // ---------------- proj path (frozen math, 2 tiles/block) -------
        int pb = blockIdx.x - nbin;
        int rel = pb >= tb1;
        int tb = rel ? pb - tb1 : pb;
        const float* x = rel ? x2 : x1;
        const float* Wy = rel ? Wy2 : Wy1;
        const float* Ws = rel ? Ws2 : Ws1;
        _Float16* y = rel ? y2 : y1;
        _Float16* s = rel ? s2 : s1;
        int N = rel ? N2 : N1;

        // weights: 512 threads load both 64x32 matrices (shared by both tiles)
        {
            const float4* a = (const float4*)Wy;
            const float4* b = (const float4*)Ws;
            ((float4*)&sm.pj.wyl[0][0])[tid] = a[tid];
            ((float4*)&sm.pj.wsl[0][0])[tid] = b[tid];
        }
        int h = tid >> 8;               // which 64-node tile (0/1)
        int t = tid & 255;
        int base = (tb * 2 + h) << 6;
#pragma unroll
        for (int i = 0; i < 4; i++) {
            int idx = i * 256 + t;
            int row = idx >> 4, c4 = (idx & 15) << 2;
            int node = base + row;
            float4 v = (node < N) ? *(const float4*)(x + ((size_t)node << 6) + c4)
                                  : make_float4(0.f, 0.f, 0.f, 0.f);
            *(float4*)&sm.pj.xs[h][row][c4] = v;
        }
        __syncthreads();

        int node = t & 63;
        int ob = (t >> 6) << 3;
        float ay[8] = {0,0,0,0,0,0,0,0};
        float as_[8] = {0,0,0,0,0,0,0,0};
#pragma unroll
        for (int kc = 0; kc < 16; kc++) {
            float4 xv = *(float4*)&sm.pj.xs[h][node][kc << 2];
#pragma unroll
            for (int kk = 0; kk < 4; kk++) {
                int k = (kc << 2) + kk;
                float xk = (kk == 0) ? xv.x : (kk == 1) ? xv.y : (kk == 2) ? xv.z : xv.w;
                float4 a = *(float4*)&sm.pj.wyl[k][ob];
                float4 b = *(float4*)&sm.pj.wyl[k][ob + 4];
                float4 c = *(float4*)&sm.pj.wsl[k][ob];
                float4 d = *(float4*)&sm.pj.wsl[k][ob + 4];
                ay[0] += xk * a.x; ay[1] += xk * a.y; ay[2] += xk * a.z; ay[3] += xk * a.w;
                ay[4] += xk * b.x; ay[5] += xk * b.y; ay[6] += xk * b.z; ay[7] += xk * b.w;
                as_[0] += xk * c.x; as_[1] += xk * c.y; as_[2] += xk * c.z; as_[3] += xk * c.w;
                as_[4] += xk * d.x; as_[5] += xk * d.y; as_[6] += xk * d.z; as_[7] += xk * d.w;
            }
        }
        int ng = base + node;
        if (ng < N) {
            union { _Float16 hh[8]; uint4 v; } uy, us;
#pragma unroll
            for (int j = 0; j < 8; j++) { uy.hh[j] = (_Float16)ay[j]; us.hh[j] = (_Float16)as_[j]; }
            *(uint4*)(y + ((size_t)ng << 5) + ob) = uy.v;
            *(uint4*)(s + ((size_t)ng << 5) + ob) = us.v;
        }
    }
}

// ---------------------------------------------------------------------------
// FUSED sort+pull (frozen structure from R8, 63us). NEW: computes the head
// constants (v2l/v2r) per-block in LDS instead of reading precomputed hconst
// (kinit deleted); block 0 additionally writes cbias to workspace for pull_l2.
__global__ void __launch_bounds__(512, 1) sortpull(
    const unsigned int* __restrict__ Pp, const int* __restrict__ gcur_p,
    const _Float16* __restrict__ y_c, const _Float16* __restrict__ sp,
    const float* __restrict__ b_p, float* __restrict__ u_p, int NP, int nbP,
    const unsigned int* __restrict__ Pc, const int* __restrict__ gcur_c,
    const _Float16* __restrict__ y_p, const _Float16* __restrict__ sc_,
    const float* __restrict__ b_c, float* __restrict__ t_c, int NC, int nbC,
    const float* __restrict__ W2l, const float* __restrict__ W2r,
    const float* __restrict__ b2, const float* __restrict__ Wlin,
    const float* __restrict__ blin, float* __restrict__ cbout,
    int* __restrict__ ss_p, int* __restrict__ ro_p, int* __restrict__ dg_p) {
    // XCD-affine mapping: xcd = blockIdx%8; rel0 on xcd 0-3, rel1 on 4-7.
    int x = blockIdx.x;
    int xcd = x & 7, k = x >> 3;
    int rel = xcd >= 4;
    int b = k * 4 + (xcd & 3);
    int nb = rel ? nbC : nbP;
    if (b >= nb) return;

    const unsigned int* P = (rel ? Pc : Pp) + (size_t)b * CAP;
    int m = min((rel ? gcur_c : gcur_p)[b], CAP);
    const _Float16* y = rel ? y_p : y_c;
    const _Float16* sf = rel ? sc_ : sp;
    const float* bv = rel ? b_c : b_p;
    float* tgt = rel ? t_c : u_p;
    int N = rel ? NC : NP;

    __shared__ int cnt[BSZ];
    __shared__ int excl[BSZ];
    __shared__ int cur[BSZ];
    __shared__ int wsum[4];
    __shared__ float hc[64];
    __shared__ int stage[CAP];

    int d0 = b << BB;
    int nd = min(BSZ, N - d0);
    int tid = threadIdx.x;

    // head constants: v2l = W2l@Wlin (hc[0..31]), v2r = W2r@Wlin (hc[32..63])
    if (tid < 64) {
        const float* W = (tid < 32) ? W2l : W2r;
        int kk = tid & 31;
        float acc = 0.0f;
#pragma unroll
        for (int j = 0; j < 32; j++) acc += W[kk * 32 + j] * Wlin[j];
        hc[tid] = acc;
    }
    if (blockIdx.x == 0 && tid == 64) {
        float acc = blin[0];
#pragma unroll
        for (int j = 0; j < 32; j++) acc += b2[j] * Wlin[j];
        *cbout = acc;   // cbias for pull_l2
    }

    // ---- phase 1: counting sort (frozen) ----
    if (tid < BSZ) cnt[tid] = 0;
    __syncthreads();
    for (int i = tid; i < m; i += 512) atomicAdd(&cnt[P[i] & (BSZ - 1)], 1);
    __syncthreads();
    int lane = tid & 63, wid = tid >> 6;
    if (tid < BSZ) {
        int v = cnt[tid], sc = v;
#pragma unroll
        for (int off = 1; off < 64; off <<= 1) {
            int t = __shfl_up(sc, off, 64);
            if (lane >= off) sc += t;
        }
        if (lane == 63) wsum[wid] = sc;
        int vkeep = v, sckeep = sc;
        __syncthreads();
        int woff = 0;
        for (int w = 0; w < wid; w++) woff += wsum[w];
        int e = woff + sckeep - vkeep;
        excl[tid] = e;
        cur[tid] = e;
    } else {
        __syncthreads();
    }
    __syncthreads();
    for (int i = tid; i < m; i += 512) {
        unsigned int p = P[i];
        int slot = atomicAdd(&cur[p & (BSZ - 1)], 1);
        stage[slot] = (int)(p >> BB);
    }
    __syncthreads();

    // rel0: persist CSR for pull_l2 (ss/ro/dg of product nodes)
    if (!rel) {
        for (int i = tid; i < m; i += 512) ss_p[(size_t)b * CAP + i] = stage[i];
        if (tid < nd) {
            ro_p[d0 + tid] = b * CAP + excl[tid];
            dg_p[d0 + tid] = cnt[tid];
        }
    }

    // ---- phase 2: pull (frozen loop; srcs from LDS stage) ----
    int l = tid & 31;
    int g = tid >> 5;                 // 16 node-groups of 32 lanes
    int el = l >> 2, sub = l & 3;

    const float* v2 = rel ? hc : hc + 32;  // t_c: v2l, u_p: v2r
    float4 b0 = *(const float4*)(bv + (sub << 3));
    float4 b1 = *(const float4*)(bv + (sub << 3) + 4);
    float4 w0 = *(const float4*)(v2 + (sub << 3));
    float4 w1 = *(const float4*)(v2 + (sub << 3) + 4);
    float bb[8] = {b0.x, b0.y, b0.z, b0.w, b1.x, b1.y, b1.z, b1.w};
    float ww[8] = {w0.x, w0.y, w0.z, w0.w, w1.x, w1.y, w1.z, w1.w};

    union U { uint4 v; half8 h; };
    for (int nl = g; nl < nd; nl += 16) {
        int node = d0 + nl;
        int start = excl[nl], deg = cnt[nl];

        half8 acc8 = (half8)(_Float16)0;
        for (int base = 0; base < deg; base += 16) {
            int j0 = base + el, j1 = base + 8 + el;
            bool v0 = j0 < deg, v1 = j1 < deg;
            int s0 = v0 ? stage[start + j0] : 0;
            int s1 = v1 ? stage[start + j1] : 0;
            U q0, q1;
            if (v0) q0.v = *(const uint4*)(y + ((size_t)s0 << 5) + (sub << 3));
            if (v1) q1.v = *(const uint4*)(y + ((size_t)s1 << 5) + (sub << 3));
            if (v0) acc8 += q0.h;
            if (v1) acc8 += q1.h;
        }
#pragma unroll
        for (int off = 4; off <= 16; off <<= 1) {
            U t, r;
            t.h = acc8;
            r.v.x = __shfl_xor(t.v.x, off, 32);
            r.v.y = __shfl_xor(t.v.y, off, 32);
            r.v.z = __shfl_xor(t.v.z, off, 32);
            r.v.w = __shfl_xor(t.v.w, off, 32);
            acc8 += r.h;
        }

        float invd = 1.0f / fmaxf((float)deg, 1.0f);
        union { uint4 v; _Float16 h[8]; } us;
        us.v = *(const uint4*)(sf + ((size_t)node << 5) + (sub << 3));
        float p = 0.0f;
#pragma unroll
        for (int j = 0; j < 8; j++) {
            float r = bb[j] + (float)us.h[j] + (float)acc8[j] * invd;
            p += fmaxf(r, 0.0f) * ww[j];
        }
        p += __shfl_xor(p, 1, 32);
        p += __shfl_xor(p, 2, 32);
        if (l == 0) tgt[node] = p;
    }
}

// ---------------------------------------------------------------------------
// layer-2 scalar pull (frozen): logit = mean t_c[src] + u_p[node] + cbias
__global__ void pull_l2_scalar(const int* __restrict__ ro, const int* __restrict__ dg,
                               const int* __restrict__ ss,
                               const float* __restrict__ t_c, const float* __restrict__ u_p,
                               const float* __restrict__ hconst,
                               float* __restrict__ out, int N) {
    int gid = blockIdx.x * blockDim.x + threadIdx.x;
    int node = gid >> 2, ln = gid & 3;
    if (node >= N) return;
    int s = ro[node], deg = dg[node], e = s + deg;
    float acc = 0.0f;
    for (int j = s + ln; j < e; j += 4) acc += t_c[ss[j]];
    acc += __shfl_xor(acc, 1, 4);
    acc += __shfl_xor(acc, 2, 4);
    if (ln == 0) {
        float logit = acc / fmaxf((float)deg, 1.0f) + u_p[node] + hconst[64];
        out[node] = 1.0f / (1.0f + expf(-logit));
    }
}

// ---------------------------------------------------------------------------
extern "C" void kernel_launch(void* const* d_in, const int* in_sizes, int n_in,
                              void* d_out, int out_size, void* d_ws, size_t ws_size,
                              hipStream_t stream) {
    const float* xc    = (const float*)d_in[0];
    const float* xp    = (const float*)d_in[1];
    const int*   e_c2p = (const int*)d_in[2];   // src=cust, dst=prod
    const int*   e_p2c = (const int*)d_in[3];   // src=prod, dst=cust
    const float* W1l_r1 = (const float*)d_in[4];
    const float* b1_r1  = (const float*)d_in[5];
    const float* W1r_r1 = (const float*)d_in[6];
    const float* W1l_r2 = (const float*)d_in[7];
    const float* b1_r2  = (const float*)d_in[8];
    const float* W1r_r2 = (const float*)d_in[9];
    const float* W2l_r1 = (const float*)d_in[10];
    const float* b2_r1  = (const float*)d_in[11];
    const float* W2r_r1 = (const float*)d_in[12];
    const float* Wlin  = (const float*)d_in[16];
    const float* blin  = (const float*)d_in[17];
    float* out = (float*)d_out;

    const int NC = in_sizes[0] / 64;
    const int NP = in_sizes[1] / 64;
    const int E  = in_sizes[2] / 2;
    const int nbP = (NP + BSZ - 1) >> BB;
    const int nbC = (NC + BSZ - 1) >> BB;

    // ---- workspace layout ----
    char* w = (char*)d_ws;
    int* gcur_p = (int*)w;  w += NBMAX * 4;     // zeroed together (memset)
    int* gcur_c = (int*)w;  w += NBMAX * 4;
    float* hconst = (float*)w; w += 68 * 4;     // only [64] (cbias) used now
    w = (char*)(((uintptr_t)w + 255) & ~(uintptr_t)255);
    unsigned int* P_p = (unsigned int*)w;  w += (size_t)nbP * CAP * 4;
    unsigned int* P_c = (unsigned int*)w;  w += (size_t)nbC * CAP * 4;
    int* ss_p = (int*)w;    w += (size_t)nbP * CAP * 4;
    int* ro_p = (int*)w;    w += (size_t)NP * 4;
    int* dg_p = (int*)w;    w += (size_t)NP * 4;
    w = (char*)(((uintptr_t)w + 255) & ~(uintptr_t)255);
    _Float16* y_c = (_Float16*)w; w += (size_t)NC * 32 * 2;
    _Float16* y_p = (_Float16*)w; w += (size_t)NP * 32 * 2;
    _Float16* s_p = (_Float16*)w; w += (size_t)NP * 32 * 2;  // xp @ W1r_r1
    _Float16* s_c = (_Float16*)w; w += (size_t)NC * 32 * 2;  // xc @ W1r_r2
    w = (char*)(((uintptr_t)w + 255) & ~(uintptr_t)255);
    float* t_c = (float*)w; w += (size_t)NC * 4;
    float* u_p = (float*)w; w += (size_t)NP * 4;

    const int bprB = (E + 8191) / 8192;
    const int nbin = 2 * bprB;

    // 1. zero bucket cursors (no kernel launch)
    hipMemsetAsync(gcur_p, 0, 2 * NBMAX * 4, stream);

    // 2. fused binning + projections (independent work, one launch)
    const int tbC = (NC + 127) / 128;
    const int tbP = (NP + 127) / 128;
    binproj<<<nbin + tbC + tbP, 512, 0, stream>>>(
        e_c2p, e_p2c, E, gcur_p, gcur_c, P_p, P_c, bprB, nbin,
        xc, W1l_r1, W1r_r2, y_c, s_c, NC, tbC,
        xp, W1l_r2, W1r_r1, y_p, s_p, NP);

    // 3. fused per-bucket sort + layer-1 pull (both relations, XCD-affine)
    const int nbMax = (nbP > nbC) ? nbP : nbC;
    const int spBlocks = 8 * ((nbMax + 3) / 4);
    sortpull<<<spBlocks, 512, 0, stream>>>(
        P_p, gcur_p, y_c, s_p, b1_r1, u_p, NP, nbP,
        P_c, gcur_c, y_p, s_c, b1_r2, t_c, NC, nbC,
        W2l_r1, W2r_r1, b2_r1, Wlin, blin, hconst + 64,
        ss_p, ro_p, dg_p);

    // 4. layer-2 scalar pull + sigmoid (4B gathers from 400KB table)
    pull_l2_scalar<<<(NP * 4 + 255) / 256, 256, 0, stream>>>(
        ro_p, dg_p, ss_p, t_c, u_p, hconst, out, NP);
}

// Round 10
// 252.219 us; speedup vs baseline: 1.1287x; 1.1287x over previous
//
#include <hip/hip_runtime.h>
#include <stdint.h>

#define BB 8            // bucket = dst >> 8 (256 dsts per bucket)
#define BSZ 256
#define NBMAX 512       // max buckets per relation (100000>>8 = 391)
#define CAP 6144        // bucket edge capacity (mean ~4096, ~32 sigma margin)

typedef _Float16 half8 __attribute__((ext_vector_type(8)));

// ---------------------------------------------------------------------------
// K1 (frozen, known-good): bin edges into fixed-capacity bucket regions
// P[b*CAP + slot], slots claimed via global atomic cursors.
// Packed: (src<<8 | dst&255).
__global__ void kbin(const int* __restrict__ e1, const int* __restrict__ e2, int E,
                     int* __restrict__ gcur1, int* __restrict__ gcur2,
                     unsigned int* __restrict__ P1, unsigned int* __restrict__ P2,
                     int blocksPerRel) {
    int rel = blockIdx.x >= blocksPerRel;
    int blk = rel ? blockIdx.x - blocksPerRel : blockIdx.x;
    const int* edge = rel ? e2 : e1;
    int* gcur = rel ? gcur2 : gcur1;
    unsigned int* P = rel ? P2 : P1;
    __shared__ int cnt[NBMAX];
    __shared__ int base[NBMAX];
    for (int i = threadIdx.x; i < NBMAX; i += 512) cnt[i] = 0;
    __syncthreads();
    int cbase = blk * 8192;
    int src[16], dst[16], rk[16];
#pragma unroll
    for (int k = 0; k < 16; k++) {
        int i = cbase + k * 512 + threadIdx.x;
        if (i < E) {
            src[k] = edge[i];
            dst[k] = edge[E + i];
            rk[k] = atomicAdd(&cnt[dst[k] >> BB], 1);
        }
    }
    __syncthreads();
    for (int b = threadIdx.x; b < NBMAX; b += 512)
        base[b] = cnt[b] ? atomicAdd(&gcur[b], cnt[b]) : 0;
    __syncthreads();
#pragma unroll
    for (int k = 0; k < 16; k++) {
        int i = cbase + k * 512 + threadIdx.x;
        if (i < E) {
            int b = dst[k] >> BB;
            int slot = base[b] + rk[k];
            if (slot < CAP)
                P[(size_t)b * CAP + slot] =
                    ((unsigned)src[k] << BB) | (unsigned)(dst[k] & (BSZ - 1));
        }
    }
}

// ---------------------------------------------------------------------------
// LDS-tiled fused projection (frozen, known-good ~37us, 256 thr, 1 tile).
// Block = 64 nodes, 1 node/thread; computes y=x@Wy (fp16) and s=x@Ws (fp16).
__global__ void proj_tile(
    const float* __restrict__ x1, const float* __restrict__ Wy1, const float* __restrict__ Ws1,
    _Float16* __restrict__ y1, _Float16* __restrict__ s1, int N1, int blocks1,
    const float* __restrict__ x2, const float* __restrict__ Wy2, const float* __restrict__ Ws2,
    _Float16* __restrict__ y2, _Float16* __restrict__ s2, int N2) {
    int rel = blockIdx.x >= blocks1;
    int blk = rel ? blockIdx.x - blocks1 : blockIdx.x;
    const float* x = rel ? x2 : x1;
    const float* Wy = rel ? Wy2 : Wy1;
    const float* Ws = rel ? Ws2 : Ws1;
    _Float16* y = rel ? y2 : y1;
    _Float16* s = rel ? s2 : s1;
    int N = rel ? N2 : N1;

    __shared__ float xs[64][68];
    __shared__ float wyl[64][32];
    __shared__ float wsl[64][32];

    int tid = threadIdx.x;
    {
        const float4* a = (const float4*)Wy;
        const float4* b = (const float4*)Ws;
        float4* la = (float4*)&wyl[0][0];
        float4* lb = (float4*)&wsl[0][0];
        la[tid] = a[tid];
        la[tid + 256] = a[tid + 256];
        lb[tid] = b[tid];
        lb[tid + 256] = b[tid + 256];
    }
    int base = blk << 6;
#pragma unroll
    for (int i = 0; i < 4; i++) {
        int idx = i * 256 + tid;
        int row = idx >> 4, c4 = (idx & 15) << 2;
        int node = base + row;
        float4 v = (node < N) ? *(const float4*)(x + ((size_t)node << 6) + c4)
                              : make_float4(0.f, 0.f, 0.f, 0.f);
        *(float4*)&xs[row][c4] = v;
    }
    __syncthreads();

    int node = tid & 63;
    int ob = (tid >> 6) << 3;
    float ay[8] = {0,0,0,0,0,0,0,0};
    float as_[8] = {0,0,0,0,0,0,0,0};
#pragma unroll
    for (int kc = 0; kc < 16; kc++) {
        float4 xv = *(float4*)&xs[node][kc << 2];
#pragma unroll
        for (int kk = 0; kk < 4; kk++) {
            int k = (kc << 2) + kk;
            float xk = (kk == 0) ? xv.x : (kk == 1) ? xv.y : (kk == 2) ? xv.z : xv.w;
            float4 a = *(float4*)&wyl[k][ob];
            float4 b = *(float4*)&wyl[k][ob + 4];
            float4 c = *(float4*)&wsl[k][ob];
            float4 d = *(float4*)&wsl[k][ob + 4];
            ay[0] += xk * a.x; ay[1] += xk * a.y; ay[2] += xk * a.z; ay[3] += xk * a.w;
            ay[4] += xk * b.x; ay[5] += xk * b.y; ay[6] += xk * b.z; ay[7] += xk * b.w;
            as_[0] += xk * c.x; as_[1] += xk * c.y; as_[2] += xk * c.z; as_[3] += xk * c.w;
            as_[4] += xk * d.x; as_[5] += xk * d.y; as_[6] += xk * d.z; as_[7] += xk * d.w;
        }
    }
    int ng = base + node;
    if (ng < N) {
        union { _Float16 h[8]; uint4 v; } uy, us;
#pragma unroll
        for (int j = 0; j < 8; j++) { uy.h[j] = (_Float16)ay[j]; us.h[j] = (_Float16)as_[j]; }
        *(uint4*)(y + ((size_t)ng << 5) + ob) = uy.v;
        *(uint4*)(s + ((size_t)ng << 5) + ob) = us.v;
    }
}

// ---------------------------------------------------------------------------
// FUSED sort+pull. NEW vs R8/R9: 2 blocks per (relation, bucket) — each
// duplicates the cheap LDS counting-sort but pulls only half the 256 dst
// nodes. Grid 784 -> 1568 blocks (~6/CU queued vs 3) to hide gather latency
// (R8 showed 40% occupancy, 21% HBM => latency-bound). half-0 block also
// persists CSR (ss/ro/dg) for pull_l2 and computes cbias (block 0).
// XCD map unchanged: rel0 -> XCDs 0-3, rel1 -> 4-7.
__global__ void __launch_bounds__(512, 1) sortpull(
    const unsigned int* __restrict__ Pp, const int* __restrict__ gcur_p,
    const _Float16* __restrict__ y_c, const _Float16* __restrict__ sp,
    const float* __restrict__ b_p, float* __restrict__ u_p, int NP, int nbP,
    const unsigned int* __restrict__ Pc, const int* __restrict__ gcur_c,
    const _Float16* __restrict__ y_p, const _Float16* __restrict__ sc_,
    const float* __restrict__ b_c, float* __restrict__ t_c, int NC, int nbC,
    const float* __restrict__ W2l, const float* __restrict__ W2r,
    const float* __restrict__ b2, const float* __restrict__ Wlin,
    const float* __restrict__ blin, float* __restrict__ cbout,
    int* __restrict__ ss_p, int* __restrict__ ro_p, int* __restrict__ dg_p) {
    // xcd = blockIdx%8; rel0 on xcd 0-3, rel1 on 4-7; k>>1 walks buckets,
    // k&1 selects which half of the bucket's nodes this block pulls.
    int x = blockIdx.x;
    int xcd = x & 7, k = x >> 3;
    int rel = xcd >= 4;
    int half = k & 1;
    int b = (k >> 1) * 4 + (xcd & 3);
    int nb = rel ? nbC : nbP;
    if (b >= nb) return;

    const unsigned int* P = (rel ? Pc : Pp) + (size_t)b * CAP;
    int m = min((rel ? gcur_c : gcur_p)[b], CAP);
    const _Float16* y = rel ? y_p : y_c;
    const _Float16* sf = rel ? sc_ : sp;
    const float* bv = rel ? b_c : b_p;
    float* tgt = rel ? t_c : u_p;
    int N = rel ? NC : NP;

    __shared__ int cnt[BSZ];
    __shared__ int excl[BSZ];
    __shared__ int cur[BSZ];
    __shared__ int wsum[4];
    __shared__ float hc[64];
    __shared__ int stage[CAP];

    int d0 = b << BB;
    int nd = min(BSZ, N - d0);
    int tid = threadIdx.x;

    // head constants: v2l = W2l@Wlin (hc[0..31]), v2r = W2r@Wlin (hc[32..63])
    if (tid < 64) {
        const float* W = (tid < 32) ? W2l : W2r;
        int kk = tid & 31;
        float acc = 0.0f;
#pragma unroll
        for (int j = 0; j < 32; j++) acc += W[kk * 32 + j] * Wlin[j];
        hc[tid] = acc;
    }
    if (blockIdx.x == 0 && tid == 64) {
        float acc = blin[0];
#pragma unroll
        for (int j = 0; j < 32; j++) acc += b2[j] * Wlin[j];
        *cbout = acc;   // cbias for pull_l2
    }

    // ---- phase 1: counting sort (frozen algorithm) ----
    if (tid < BSZ) cnt[tid] = 0;
    __syncthreads();
    for (int i = tid; i < m; i += 512) atomicAdd(&cnt[P[i] & (BSZ - 1)], 1);
    __syncthreads();
    int lane = tid & 63, wid = tid >> 6;
    if (tid < BSZ) {
        int v = cnt[tid], sc = v;
#pragma unroll
        for (int off = 1; off < 64; off <<= 1) {
            int t = __shfl_up(sc, off, 64);
            if (lane >= off) sc += t;
        }
        if (lane == 63) wsum[wid] = sc;
        int vkeep = v, sckeep = sc;
        __syncthreads();
        int woff = 0;
        for (int w = 0; w < wid; w++) woff += wsum[w];
        int e = woff + sckeep - vkeep;
        excl[tid] = e;
        cur[tid] = e;
    } else {
        __syncthreads();
    }
    __syncthreads();
    for (int i = tid; i < m; i += 512) {
        unsigned int p = P[i];
        int slot = atomicAdd(&cur[p & (BSZ - 1)], 1);
        stage[slot] = (int)(p >> BB);
    }
    __syncthreads();

    // rel0 half0: persist CSR for pull_l2 (ss/ro/dg of product nodes)
    if (!rel && half == 0) {
        for (int i = tid; i < m; i += 512) ss_p[(size_t)b * CAP + i] = stage[i];
        if (tid < nd) {
            ro_p[d0 + tid] = b * CAP + excl[tid];
            dg_p[d0 + tid] = cnt[tid];
        }
    }

    // ---- phase 2: pull this block's half of the nodes (frozen loop) ----
    int l = tid & 31;
    int g = tid >> 5;                 // 16 node-groups of 32 lanes
    int el = l >> 2, sub = l & 3;

    const float* v2 = rel ? hc : hc + 32;  // t_c: v2l, u_p: v2r
    float4 b0 = *(const float4*)(bv + (sub << 3));
    float4 b1 = *(const float4*)(bv + (sub << 3) + 4);
    float4 w0 = *(const float4*)(v2 + (sub << 3));
    float4 w1 = *(const float4*)(v2 + (sub << 3) + 4);
    float bb[8] = {b0.x, b0.y, b0.z, b0.w, b1.x, b1.y, b1.z, b1.w};
    float ww[8] = {w0.x, w0.y, w0.z, w0.w, w1.x, w1.y, w1.z, w1.w};

    int n0 = half << 7;               // nodes [n0, n1) of this bucket
    int n1 = min(nd, n0 + 128);

    union U { uint4 v; half8 h; };
    for (int nl = n0 + g; nl < n1; nl += 16) {
        int node = d0 + nl;
        int start = excl[nl], deg = cnt[nl];

        half8 acc8 = (half8)(_Float16)0;
        for (int base = 0; base < deg; base += 16) {
            int j0 = base + el, j1 = base + 8 + el;
            bool v0 = j0 < deg, v1 = j1 < deg;
            int s0 = v0 ? stage[start + j0] : 0;
            int s1 = v1 ? stage[start + j1] : 0;
            U q0, q1;
            if (v0) q0.v = *(const uint4*)(y + ((size_t)s0 << 5) + (sub << 3));
            if (v1) q1.v = *(const uint4*)(y + ((size_t)s1 << 5) + (sub << 3));
            if (v0) acc8 += q0.h;
            if (v1) acc8 += q1.h;
        }
#pragma unroll
        for (int off = 4; off <= 16; off <<= 1) {
            U t, r;
            t.h = acc8;
            r.v.x = __shfl_xor(t.v.x, off, 32);
            r.v.y = __shfl_xor(t.v.y, off, 32);
            r.v.z = __shfl_xor(t.v.z, off, 32);
            r.v.w = __shfl_xor(t.v.w, off, 32);
            acc8 += r.h;
        }

        float invd = 1.0f / fmaxf((float)deg, 1.0f);
        union { uint4 v; _Float16 h[8]; } us;
        us.v = *(const uint4*)(sf + ((size_t)node << 5) + (sub << 3));
        float p = 0.0f;
#pragma unroll
        for (int j = 0; j < 8; j++) {
            float r = bb[j] + (float)us.h[j] + (float)acc8[j] * invd;
            p += fmaxf(r, 0.0f) * ww[j];
        }
        p += __shfl_xor(p, 1, 32);
        p += __shfl_xor(p, 2, 32);
        if (l == 0) tgt[node] = p;
    }
}

// ---------------------------------------------------------------------------
// layer-2 scalar pull (frozen): logit = mean t_c[src] + u_p[node] + cbias
__global__ void pull_l2_scalar(const int* __restrict__ ro, const int* __restrict__ dg,
                               const int* __restrict__ ss,
                               const float* __restrict__ t_c, const float* __restrict__ u_p,
                               const float* __restrict__ hconst,
                               float* __restrict__ out, int N) {
    int gid = blockIdx.x * blockDim.x + threadIdx.x;
    int node = gid >> 2, ln = gid & 3;
    if (node >= N) return;
    int s = ro[node], deg = dg[node], e = s + deg;
    float acc = 0.0f;
    for (int j = s + ln; j < e; j += 4) acc += t_c[ss[j]];
    acc += __shfl_xor(acc, 1, 4);
    acc += __shfl_xor(acc, 2, 4);
    if (ln == 0) {
        float logit = acc / fmaxf((float)deg, 1.0f) + u_p[node] + hconst[64];
        out[node] = 1.0f / (1.0f + expf(-logit));
    }
}

// ---------------------------------------------------------------------------
extern "C" void kernel_launch(void* const* d_in, const int* in_sizes, int n_in,
                              void* d_out, int out_size, void* d_ws, size_t ws_size,
                              hipStream_t stream) {
    const float* xc    = (const float*)d_in[0];
    const float* xp    = (const float*)d_in[1];
    const int*   e_c2p = (const int*)d_in[2];   // src=cust, dst=prod
    const int*   e_p2c = (const int*)d_in[3];   // src=prod, dst=cust
    const float* W1l_r1 = (const float*)d_in[4];
    const float* b1_r1  = (const float*)d_in[5];
    const float* W1r_r1 = (const float*)d_in[6];
    const float* W1l_r2 = (const float*)d_in[7];
    const float* b1_r2  = (const float*)d_in[8];
    const float* W1r_r2 = (const float*)d_in[9];
    const float* W2l_r1 = (const float*)d_in[10];
    const float* b2_r1  = (const float*)d_in[11];
    const float* W2r_r1 = (const float*)d_in[12];
    const float* Wlin  = (const float*)d_in[16];
    const float* blin  = (const float*)d_in[17];
    float* out = (float*)d_out;

    const int NC = in_sizes[0] / 64;
    const int NP = in_sizes[1] / 64;
    const int E  = in_sizes[2] / 2;
    const int nbP = (NP + BSZ - 1) >> BB;
    const int nbC = (NC + BSZ - 1) >> BB;

    // ---- workspace layout ----
    char* w = (char*)d_ws;
    int* gcur_p = (int*)w;  w += NBMAX * 4;     // zeroed together (memset)
    int* gcur_c = (int*)w;  w += NBMAX * 4;
    float* hconst = (float*)w; w += 68 * 4;     // only [64] (cbias) used now
    w = (char*)(((uintptr_t)w + 255) & ~(uintptr_t)255);
    unsigned int* P_p = (unsigned int*)w;  w += (size_t)nbP * CAP * 4;
    unsigned int* P_c = (unsigned int*)w;  w += (size_t)nbC * CAP * 4;
    int* ss_p = (int*)w;    w += (size_t)nbP * CAP * 4;
    int* ro_p = (int*)w;    w += (size_t)NP * 4;
    int* dg_p = (int*)w;    w += (size_t)NP * 4;
    w = (char*)(((uintptr_t)w + 255) & ~(uintptr_t)255);
    _Float16* y_c = (_Float16*)w; w += (size_t)NC * 32 * 2;
    _Float16* y_p = (_Float16*)w; w += (size_t)NP * 32 * 2;
    _Float16* s_p = (_Float16*)w; w += (size_t)NP * 32 * 2;  // xp @ W1r_r1
    _Float16* s_c = (_Float16*)w; w += (size_t)NC * 32 * 2;  // xc @ W1r_r2
    w = (char*)(((uintptr_t)w + 255) & ~(uintptr_t)255);
    float* t_c = (float*)w; w += (size_t)NC * 4;
    float* u_p = (float*)w; w += (size_t)NP * 4;

    const int bprB = (E + 8191) / 8192;

    // 1. zero bucket cursors (no kernel launch)
    hipMemsetAsync(gcur_p, 0, 2 * NBMAX * 4, stream);

    // 2. bucket binning (frozen)
    kbin<<<2 * bprB, 512, 0, stream>>>(e_c2p, e_p2c, E, gcur_p, gcur_c, P_p, P_c, bprB);

    // 3. LDS-tiled fused projections (frozen)
    const int tblocksC = (NC + 63) / 64;
    const int tblocksP = (NP + 63) / 64;
    proj_tile<<<tblocksC + tblocksP, 256, 0, stream>>>(
        xc, W1l_r1, W1r_r2, y_c, s_c, NC, tblocksC,
        xp, W1l_r2, W1r_r1, y_p, s_p, NP);

    // 4. fused per-bucket sort + layer-1 pull, 2 blocks/bucket (node halves)
    const int nbMax = (nbP > nbC) ? nbP : nbC;
    const int spBlocks = 8 * 2 * ((nbMax + 3) / 4);
    sortpull<<<spBlocks, 512, 0, stream>>>(
        P_p, gcur_p, y_c, s_p, b1_r1, u_p, NP, nbP,
        P_c, gcur_c, y_p, s_c, b1_r2, t_c, NC, nbC,
        W2l_r1, W2r_r1, b2_r1, Wlin, blin, hconst + 64,
        ss_p, ro_p, dg_p);

    // 5. layer-2 scalar pull + sigmoid (4B gathers from 400KB table)
    pull_l2_scalar<<<(NP * 4 + 255) / 256, 256, 0, stream>>>(
        ro_p, dg_p, ss_p, t_c, u_p, hconst, out, NP);
}